// Round 5
// baseline (24832.372 us; speedup 1.0000x reference)
//
#include <hip/hip_runtime.h>
#include <hip/hip_cooperative_groups.h>

static constexpr int Bc = 128;   // batch
static constexpr int Tc = 256;   // timesteps
static constexpr int Ec = 512;   // input embed
static constexpr int Hc = 1024;  // hidden

using bf16x8 = __attribute__((ext_vector_type(8))) short;
using f32x4  = __attribute__((ext_vector_type(4))) float;

__device__ __forceinline__ unsigned short f2bf(float f) {
  unsigned int u = __float_as_uint(f);
  u += 0x7FFFu + ((u >> 16) & 1u);
  return (unsigned short)(u >> 16);
}
__device__ __forceinline__ float sigm(float x) { return 1.0f / (1.0f + __expf(-x)); }

#define MFMA16(A, Bf, C) __builtin_amdgcn_mfma_f32_16x16x32_bf16((A), (Bf), (C), 0, 0, 0)

// acquire-poll on own 64B-strided slot (round-3-proven primitive strength)
__device__ __forceinline__ void poll_acq(const int* p, int tgt) {
  while (__hip_atomic_load(p, __ATOMIC_ACQUIRE, __HIP_MEMORY_SCOPE_AGENT) < tgt)
    __builtin_amdgcn_s_sleep(1);
}
__device__ __forceinline__ void sig(int* p, int v) {
  __hip_atomic_store(p, v, __ATOMIC_RELEASE, __HIP_MEMORY_SCOPE_AGENT);
}

// ----------------- prep kernels -----------------
__global__ void k_cvt_bf16(const float* __restrict__ src, unsigned short* __restrict__ dst, int n) {
  int i = (blockIdx.x * blockDim.x + threadIdx.x) * 4;
  if (i + 3 < n) {
    f32x4 v = *(const f32x4*)(src + i);
    *(ushort4*)(dst + i) = make_ushort4(f2bf(v[0]), f2bf(v[1]), f2bf(v[2]), f2bf(v[3]));
  }
}

__global__ void k_prep_small(const float* __restrict__ bih0, const float* __restrict__ bhh0,
                             float* __restrict__ b0s,
                             unsigned short* __restrict__ h1buf, unsigned short* __restrict__ h2buf,
                             int* __restrict__ f1, int* __restrict__ f2) {
  int i = blockIdx.x * blockDim.x + threadIdx.x;  // grid covers 4*Bc*Hc = 524288
  if (i < 4096) b0s[i] = bih0[i] + bhh0[i];
  h1buf[i] = 0; h2buf[i] = 0;
  if (i < 128 * 16) { f1[i] = 0; f2[i] = 0; }
}

// ----------------- layer-0 bulk GEMM (no recurrence; f-gate dead) -----------------
__global__ __launch_bounds__(512, 1) void k_l0(
    const unsigned short* __restrict__ xb, const unsigned short* __restrict__ W0,
    const float* __restrict__ b0s, unsigned short* __restrict__ H0)
{
  const int tid = threadIdx.x;
  const int lane = tid & 63, wid = tid >> 6;
  const int wM = wid >> 2, wN = wid & 3;           // 8 waves: 2(M) x 4(N)
  const int rowbase = blockIdx.x * 32 + wM * 16;
  const int jbase   = blockIdx.y * 64 + wN * 16;
  const int ri = lane & 15, kg = lane >> 4;

  const int r = rowbase + ri;
  const int t = r >> 7, b = r & (Bc - 1);
  const unsigned short* arow = xb + ((size_t)b * Tc + t) * Ec + kg * 8;

  const unsigned short* w0r = W0 + ((size_t)(0 * Hc + jbase + ri)) * Ec + kg * 8;
  const unsigned short* w2r = W0 + ((size_t)(2 * Hc + jbase + ri)) * Ec + kg * 8;
  const unsigned short* w3r = W0 + ((size_t)(3 * Hc + jbase + ri)) * Ec + kg * 8;

  f32x4 ai = {0,0,0,0}, ag = {0,0,0,0}, ao = {0,0,0,0};
#pragma unroll
  for (int kk = 0; kk < Ec / 32; ++kk) {
    bf16x8 a = *(const bf16x8*)(arow + kk * 32);
    ai = MFMA16(a, *(const bf16x8*)(w0r + kk * 32), ai);
    ag = MFMA16(a, *(const bf16x8*)(w2r + kk * 32), ag);
    ao = MFMA16(a, *(const bf16x8*)(w3r + kk * 32), ao);
  }
  const int j = jbase + ri;
  const float bi = b0s[j], bg = b0s[2 * Hc + j], bo = b0s[3 * Hc + j];
#pragma unroll
  for (int q = 0; q < 4; ++q) {
    const int rr = rowbase + kg * 4 + q;
    float c = sigm(ai[q] + bi) * tanhf(ag[q] + bg);
    float h = sigm(ao[q] + bo) * tanhf(c);
    H0[(size_t)rr * Hc + j] = f2bf(h);
  }
}

// ----------------- recurrent kernel: round-3 compute + hardened stamp sync -----------------
// 256 WGs x 512 thr (8 waves), 1 WG/CU. WGs 0..127: layer1; 128..255: layer2.
// Sync: per-producer phase-stamp slots (64B stride). Producer: data stores ->
// all-wave fence(release, agent) -> __syncthreads -> tid0 release-store stamp.
// Consumer: 128 threads acquire-poll distinct slots -> __syncthreads -> all-wave
// acquire fence. No atomic RMW, no shared-line polling.
__global__ __launch_bounds__(512, 1) void k_rec(
    const unsigned short* H0,                        // [Tc*Bc][Hc] bf16 (upper half of d_out)
    const float* __restrict__ Wih, const float* __restrict__ Whh,  // [2][4096][1024] f32
    const float* __restrict__ bih, const float* __restrict__ bhh,  // [2][4096] f32
    unsigned short* h1buf, unsigned short* h2buf,    // [4][Bc][Hc] bf16
    int* f1, int* f2,                                // [128] slots x 16 ints (64B stride)
    float* out)                                      // [Tc][Bc][Hc] f32 (lower d_out)
{
  __shared__ unsigned short Wlds[2 * 64 * 64 * 8];   // 128 KiB: [tile][kstep][lane][8]
  const int tid = threadIdx.x;
  const int lane = tid & 63, wid = tid >> 6;
  const int bid = blockIdx.x;
  const int layer = bid >> 7;
  const int w = bid & 127;
  const int j0 = w * 8;
  const int ri = lane & 15, kg = lane >> 4;

  // ---- prologue: weights fp32 -> bf16 into LDS, fragment-major ----
  const size_t lw = (size_t)layer * 4096 * 1024;
  for (int s = tid; s < 2 * 64 * 64; s += 512) {
    const int l   = s & 63;
    const int kkg = (s >> 6) & 63;
    const int t   = s >> 12;
    const int rr  = l & 15;
    const int gate = t * 2 + (rr >> 3);
    const int R = gate * 1024 + j0 + (rr & 7);
    const int k = kkg * 32 + (l >> 4) * 8;
    const float* src = (k < 1024) ? (Wih + lw + (size_t)R * 1024 + k)
                                  : (Whh + lw + (size_t)R * 1024 + (k - 1024));
    f32x4 v0 = *(const f32x4*)src;
    f32x4 v1 = *(const f32x4*)(src + 4);
    ushort4* d = (ushort4*)(Wlds + (size_t)s * 8);
    d[0] = make_ushort4(f2bf(v0[0]), f2bf(v0[1]), f2bf(v0[2]), f2bf(v0[3]));
    d[1] = make_ushort4(f2bf(v1[0]), f2bf(v1[1]), f2bf(v1[2]), f2bf(v1[3]));
  }

  const int jme = j0 + (ri & 7);
  const int g0 = (ri < 8) ? 0 : 1;                  // tile0: i | f
  const int g1 = (ri < 8) ? 2 : 3;                  // tile1: g | o
  const float bias0 = bih[layer * 4096 + g0 * 1024 + jme] + bhh[layer * 4096 + g0 * 1024 + jme];
  const float bias1 = bih[layer * 4096 + g1 * 1024 + jme] + bhh[layer * 4096 + g1 * 1024 + jme];

  float creg[4] = {0.f, 0.f, 0.f, 0.f};

  const unsigned short* lds0 = Wlds + (size_t)lane * 8;
  const unsigned short* lds1 = Wlds + (size_t)64 * 64 * 8 + (size_t)lane * 8;
  const int arow = wid * 16 + ri;
  const bool lo = (ri < 8);

  __syncthreads();                                  // Wlds ready

  if (layer == 0) {
    // ---------------- layer 1: h1(p) = cell(H0(p), h1(p-1)) ----------------
    for (int p = 0; p < Tc; ++p) {
      // free half: A1 = H0(p), K 0..1023 (no dependency)
      const unsigned short* a1 = H0 + (size_t)p * Bc * Hc + (size_t)arow * Hc + kg * 8;
      f32x4 acc0 = {0,0,0,0}, acc1 = {0,0,0,0};
#pragma unroll
      for (int kk = 0; kk < 32; ++kk) {
        bf16x8 a = *(const bf16x8*)(a1 + kk * 32);
        acc0 = MFMA16(a, *(const bf16x8*)(lds0 + kk * 512), acc0);
        acc1 = MFMA16(a, *(const bf16x8*)(lds1 + kk * 512), acc1);
      }
      // gated half: wait h1(p-1) ready
      if (tid < 128 && p >= 1) poll_acq(f1 + tid * 16, p);
      __syncthreads();
      __builtin_amdgcn_fence(__ATOMIC_ACQUIRE, "agent");
      const unsigned short* a2 = h1buf + (size_t)((p - 1) & 3) * Bc * Hc + (size_t)arow * Hc + kg * 8;
#pragma unroll
      for (int kk = 32; kk < 64; ++kk) {
        bf16x8 a = *(const bf16x8*)(a2 + (kk - 32) * 32);
        acc0 = MFMA16(a, *(const bf16x8*)(lds0 + kk * 512), acc0);
        acc1 = MFMA16(a, *(const bf16x8*)(lds1 + kk * 512), acc1);
      }
      // cell epilogue into registers
      float hn[4];
#pragma unroll
      for (int q = 0; q < 4; ++q) {
        float x0 = acc0[q] + bias0;
        float x1 = acc1[q] + bias1;
        float p0 = __shfl_xor(x0, 8);
        float p1 = __shfl_xor(x1, 8);
        float gi = lo ? x0 : p0;
        float gf = lo ? p0 : x0;
        float gg = lo ? x1 : p1;
        float go = lo ? p1 : x1;
        float cn = sigm(gf) * creg[q] + sigm(gi) * tanhf(gg);
        hn[q] = sigm(go) * tanhf(cn);
        creg[q] = cn;
      }
      // recycle wait: h1buf[p&3] last read by layer-2 step p-4
      if (tid < 128 && p >= 4) poll_acq(f2 + tid * 16, p - 3);
      __syncthreads();
      unsigned short* hb = h1buf + (size_t)(p & 3) * Bc * Hc;
      if (lo) {
#pragma unroll
        for (int q = 0; q < 4; ++q) {
          const int rr = wid * 16 + kg * 4 + q;
          hb[(size_t)rr * Hc + jme] = f2bf(hn[q]);
        }
      }
      __builtin_amdgcn_fence(__ATOMIC_RELEASE, "agent");  // every wave: drain + L2 writeback
      __syncthreads();
      if (tid == 0) sig(f1 + w * 16, p + 1);
    }
  } else {
    // ---------------- layer 2: h2(s) = cell(h1(s), h2(s-1)) ----------------
    for (int s = 0; s < Tc; ++s) {
      // own-chain half first: wait h2(s-1)
      if (tid < 128 && s >= 1) poll_acq(f2 + tid * 16, s);
      __syncthreads();
      __builtin_amdgcn_fence(__ATOMIC_ACQUIRE, "agent");
      const unsigned short* a2 = h2buf + (size_t)((s - 1) & 3) * Bc * Hc + (size_t)arow * Hc + kg * 8;
      f32x4 acc0 = {0,0,0,0}, acc1 = {0,0,0,0};
#pragma unroll
      for (int kk = 32; kk < 64; ++kk) {
        bf16x8 a = *(const bf16x8*)(a2 + (kk - 32) * 32);
        acc0 = MFMA16(a, *(const bf16x8*)(lds0 + kk * 512), acc0);
        acc1 = MFMA16(a, *(const bf16x8*)(lds1 + kk * 512), acc1);
      }
      // cross-layer half: wait h1(s)
      if (tid < 128) poll_acq(f1 + tid * 16, s + 1);
      __syncthreads();
      __builtin_amdgcn_fence(__ATOMIC_ACQUIRE, "agent");
      const unsigned short* a1 = h1buf + (size_t)(s & 3) * Bc * Hc + (size_t)arow * Hc + kg * 8;
#pragma unroll
      for (int kk = 0; kk < 32; ++kk) {
        bf16x8 a = *(const bf16x8*)(a1 + kk * 32);
        acc0 = MFMA16(a, *(const bf16x8*)(lds0 + kk * 512), acc0);
        acc1 = MFMA16(a, *(const bf16x8*)(lds1 + kk * 512), acc1);
      }
      // cell epilogue + stores
      unsigned short* hb = h2buf + (size_t)(s & 3) * Bc * Hc;
      float* po = out + (size_t)s * Bc * Hc;
#pragma unroll
      for (int q = 0; q < 4; ++q) {
        float x0 = acc0[q] + bias0;
        float x1 = acc1[q] + bias1;
        float p0 = __shfl_xor(x0, 8);
        float p1 = __shfl_xor(x1, 8);
        float gi = lo ? x0 : p0;
        float gf = lo ? p0 : x0;
        float gg = lo ? x1 : p1;
        float go = lo ? p1 : x1;
        float cn = sigm(gf) * creg[q] + sigm(gi) * tanhf(gg);
        float hnv = sigm(go) * tanhf(cn);
        creg[q] = cn;
        const int rr = wid * 16 + kg * 4 + q;
        if (lo) {
          hb[(size_t)rr * Hc + jme] = f2bf(hnv);
          po[(size_t)rr * Hc + jme] = hnv;
        }
      }
      __builtin_amdgcn_fence(__ATOMIC_RELEASE, "agent");
      __syncthreads();
      if (tid == 0) sig(f2 + w * 16, s + 1);
    }
  }
}

// ----------------- launcher -----------------
extern "C" void kernel_launch(void* const* d_in, const int* in_sizes, int n_in,
                              void* d_out, int out_size, void* d_ws, size_t ws_size,
                              hipStream_t stream) {
  const float* x     = (const float*)d_in[0];
  const float* W_ih0 = (const float*)d_in[1];
  // d_in[2] = W_hh0 (unused: layer-0 state is always zero)
  const float* b_ih0 = (const float*)d_in[3];
  const float* b_hh0 = (const float*)d_in[4];
  const float* W_ihr = (const float*)d_in[5];
  const float* W_hhr = (const float*)d_in[6];
  const float* b_ihr = (const float*)d_in[7];
  const float* b_hhr = (const float*)d_in[8];

  char* ws = (char*)d_ws;
  constexpr size_t W0B_OFF = 0;                                  // 4 MB
  constexpr size_t XB_OFF  = W0B_OFF + (size_t)4096 * 512 * 2;   // 32 MB
  constexpr size_t B0S_OFF = XB_OFF + (size_t)Bc * Tc * Ec * 2;  // 16 KB
  constexpr size_t H1B_OFF = B0S_OFF + 4096 * 4;                 // 1 MB
  constexpr size_t H2B_OFF = H1B_OFF + (size_t)4 * Bc * Hc * 2;  // 1 MB
  constexpr size_t F1_OFF  = H2B_OFF + (size_t)4 * Bc * Hc * 2;  // 8 KB
  constexpr size_t F2_OFF  = F1_OFF + 128 * 16 * 4;              // 8 KB

  unsigned short* W0b = (unsigned short*)(ws + W0B_OFF);
  unsigned short* xb  = (unsigned short*)(ws + XB_OFF);
  float* b0s = (float*)(ws + B0S_OFF);
  unsigned short* h1buf = (unsigned short*)(ws + H1B_OFF);
  unsigned short* h2buf = (unsigned short*)(ws + H2B_OFF);
  int* f1 = (int*)(ws + F1_OFF);
  int* f2 = (int*)(ws + F2_OFF);

  // H0 (bf16 [T][B][H], 64 MB) lives in the upper half of d_out. out[s] (written at
  // layer-2 step s, after f1 >= s+1) only overlaps H0[q] for q = 2(s-128)+{0,1} <= s,
  // i.e. strictly after layer 1 finished reading H0[q]. Verified byte-exact.
  unsigned short* H0 = (unsigned short*)d_out + (size_t)Tc * Bc * Hc;
  float* out = (float*)d_out;

  int n0 = 4096 * 512;
  k_cvt_bf16<<<n0 / 1024, 256, 0, stream>>>(W_ih0, W0b, n0);
  int nx = Bc * Tc * Ec;
  k_cvt_bf16<<<nx / 1024, 256, 0, stream>>>(x, xb, nx);
  k_prep_small<<<2048, 256, 0, stream>>>(b_ih0, b_hh0, b0s, h1buf, h2buf, f1, f2);
  k_l0<<<dim3(1024, 16), 512, 0, stream>>>(xb, W0b, b0s, H0);

  const float* Wih = W_ihr; const float* Whh = W_hhr;
  const float* bih = b_ihr; const float* bhh = b_hhr;
  void* kargs[] = { &H0, &Wih, &Whh, &bih, &bhh, &h1buf, &h2buf, &f1, &f2, &out };
  hipLaunchCooperativeKernel((void*)k_rec, dim3(256), dim3(512), kargs, 0, stream);
}

// Round 6
// 8778.470 us; speedup vs baseline: 2.8288x; 2.8288x over previous
//
#include <hip/hip_runtime.h>
#include <hip/hip_cooperative_groups.h>

static constexpr int Bc = 128;   // batch
static constexpr int Tc = 256;   // timesteps
static constexpr int Ec = 512;   // input embed
static constexpr int Hc = 1024;  // hidden

using bf16x8 = __attribute__((ext_vector_type(8))) short;
using f32x4  = __attribute__((ext_vector_type(4))) float;

__device__ __forceinline__ unsigned short f2bf(float f) {
  unsigned int u = __float_as_uint(f);
  u += 0x7FFFu + ((u >> 16) & 1u);
  return (unsigned short)(u >> 16);
}
__device__ __forceinline__ float sigm(float x) { return 1.0f / (1.0f + __expf(-x)); }

#define MFMA16(A, Bf, C) __builtin_amdgcn_mfma_f32_16x16x32_bf16((A), (Bf), (C), 0, 0, 0)

// ---- fence-free L3-coherent primitives (sc1 scoped ops; no wbl2/inv ever) ----
// relaxed agent poll: L3-direct load, no cache maintenance per iteration
__device__ __forceinline__ void poll_rlx(const int* p, int tgt) {
  while (__hip_atomic_load(p, __ATOMIC_RELAXED, __HIP_MEMORY_SCOPE_AGENT) < tgt)
    __builtin_amdgcn_s_sleep(1);
}
// relaxed agent stamp store (ordering provided by pre-barrier vmcnt(0) drain)
__device__ __forceinline__ void sig(int* p, int v) {
  __hip_atomic_store(p, v, __ATOMIC_RELAXED, __HIP_MEMORY_SCOPE_AGENT);
}
// L3-coherent 16B fragment load as 2x8B agent-relaxed loads (sc1: bypass stale L2)
__device__ __forceinline__ bf16x8 ldg_c(const unsigned short* p) {
  union { unsigned long long u[2]; bf16x8 v; } r;
  r.u[0] = __hip_atomic_load((const unsigned long long*)p,       __ATOMIC_RELAXED, __HIP_MEMORY_SCOPE_AGENT);
  r.u[1] = __hip_atomic_load((const unsigned long long*)(p + 4), __ATOMIC_RELAXED, __HIP_MEMORY_SCOPE_AGENT);
  return r.v;
}
// L3-coherent 2B store (sc1 write-through: lands at coherence point, no dirty L2)
__device__ __forceinline__ void stg_c(unsigned short* p, unsigned short v) {
  __hip_atomic_store(p, v, __ATOMIC_RELAXED, __HIP_MEMORY_SCOPE_AGENT);
}

// ----------------- prep kernels -----------------
__global__ void k_cvt_bf16(const float* __restrict__ src, unsigned short* __restrict__ dst, int n) {
  int i = (blockIdx.x * blockDim.x + threadIdx.x) * 4;
  if (i + 3 < n) {
    f32x4 v = *(const f32x4*)(src + i);
    *(ushort4*)(dst + i) = make_ushort4(f2bf(v[0]), f2bf(v[1]), f2bf(v[2]), f2bf(v[3]));
  }
}

__global__ void k_prep_small(const float* __restrict__ bih0, const float* __restrict__ bhh0,
                             float* __restrict__ b0s,
                             unsigned short* __restrict__ h1buf, unsigned short* __restrict__ h2buf,
                             int* __restrict__ f1, int* __restrict__ f2) {
  int i = blockIdx.x * blockDim.x + threadIdx.x;  // grid covers 4*Bc*Hc = 524288
  if (i < 4096) b0s[i] = bih0[i] + bhh0[i];
  h1buf[i] = 0; h2buf[i] = 0;
  if (i < 128 * 16) { f1[i] = 0; f2[i] = 0; }
}

// ----------------- layer-0 bulk GEMM (no recurrence; f-gate dead) -----------------
__global__ __launch_bounds__(512, 1) void k_l0(
    const unsigned short* __restrict__ xb, const unsigned short* __restrict__ W0,
    const float* __restrict__ b0s, unsigned short* __restrict__ H0)
{
  const int tid = threadIdx.x;
  const int lane = tid & 63, wid = tid >> 6;
  const int wM = wid >> 2, wN = wid & 3;           // 8 waves: 2(M) x 4(N)
  const int rowbase = blockIdx.x * 32 + wM * 16;
  const int jbase   = blockIdx.y * 64 + wN * 16;
  const int ri = lane & 15, kg = lane >> 4;

  const int r = rowbase + ri;
  const int t = r >> 7, b = r & (Bc - 1);
  const unsigned short* arow = xb + ((size_t)b * Tc + t) * Ec + kg * 8;

  const unsigned short* w0r = W0 + ((size_t)(0 * Hc + jbase + ri)) * Ec + kg * 8;
  const unsigned short* w2r = W0 + ((size_t)(2 * Hc + jbase + ri)) * Ec + kg * 8;
  const unsigned short* w3r = W0 + ((size_t)(3 * Hc + jbase + ri)) * Ec + kg * 8;

  f32x4 ai = {0,0,0,0}, ag = {0,0,0,0}, ao = {0,0,0,0};
#pragma unroll
  for (int kk = 0; kk < Ec / 32; ++kk) {
    bf16x8 a = *(const bf16x8*)(arow + kk * 32);
    ai = MFMA16(a, *(const bf16x8*)(w0r + kk * 32), ai);
    ag = MFMA16(a, *(const bf16x8*)(w2r + kk * 32), ag);
    ao = MFMA16(a, *(const bf16x8*)(w3r + kk * 32), ao);
  }
  const int j = jbase + ri;
  const float bi = b0s[j], bg = b0s[2 * Hc + j], bo = b0s[3 * Hc + j];
#pragma unroll
  for (int q = 0; q < 4; ++q) {
    const int rr = rowbase + kg * 4 + q;
    float c = sigm(ai[q] + bi) * tanhf(ag[q] + bg);
    float h = sigm(ao[q] + bo) * tanhf(c);
    H0[(size_t)rr * Hc + j] = f2bf(h);
  }
}

// ----------------- recurrent kernel: round-3 compute + fence-free L3-coherent sync ---------
// 256 WGs x 512 thr (8 waves), 1 WG/CU. WGs 0..127: layer1; 128..255: layer2.
// h-state is ONLY accessed with agent-scope relaxed (sc1) ops inside this kernel ->
// always served at the L3 coherence point; no L2 writeback/invalidate anywhere.
// Producer: sc1 data stores -> __syncthreads (pre-barrier vmcnt(0) ACKs them at L3)
// -> tid0 relaxed stamp. Consumer: relaxed polls on own 64B slot -> __syncthreads.
__global__ __launch_bounds__(512, 1) void k_rec(
    const unsigned short* H0,                        // [Tc*Bc][Hc] bf16 (upper half of d_out)
    const float* __restrict__ Wih, const float* __restrict__ Whh,  // [2][4096][1024] f32
    const float* __restrict__ bih, const float* __restrict__ bhh,  // [2][4096] f32
    unsigned short* h1buf, unsigned short* h2buf,    // [4][Bc][Hc] bf16
    int* f1, int* f2,                                // [128] slots x 16 ints (64B stride)
    float* out)                                      // [Tc][Bc][Hc] f32 (lower d_out)
{
  __shared__ unsigned short Wlds[2 * 64 * 64 * 8];   // 128 KiB: [tile][kstep][lane][8]
  const int tid = threadIdx.x;
  const int lane = tid & 63, wid = tid >> 6;
  const int bid = blockIdx.x;
  const int layer = bid >> 7;
  const int w = bid & 127;
  const int j0 = w * 8;
  const int ri = lane & 15, kg = lane >> 4;

  // ---- prologue: weights fp32 -> bf16 into LDS, fragment-major ----
  const size_t lw = (size_t)layer * 4096 * 1024;
  for (int s = tid; s < 2 * 64 * 64; s += 512) {
    const int l   = s & 63;
    const int kkg = (s >> 6) & 63;
    const int t   = s >> 12;
    const int rr  = l & 15;
    const int gate = t * 2 + (rr >> 3);
    const int R = gate * 1024 + j0 + (rr & 7);
    const int k = kkg * 32 + (l >> 4) * 8;
    const float* src = (k < 1024) ? (Wih + lw + (size_t)R * 1024 + k)
                                  : (Whh + lw + (size_t)R * 1024 + (k - 1024));
    f32x4 v0 = *(const f32x4*)src;
    f32x4 v1 = *(const f32x4*)(src + 4);
    ushort4* d = (ushort4*)(Wlds + (size_t)s * 8);
    d[0] = make_ushort4(f2bf(v0[0]), f2bf(v0[1]), f2bf(v0[2]), f2bf(v0[3]));
    d[1] = make_ushort4(f2bf(v1[0]), f2bf(v1[1]), f2bf(v1[2]), f2bf(v1[3]));
  }

  const int jme = j0 + (ri & 7);
  const int g0 = (ri < 8) ? 0 : 1;                  // tile0: i | f
  const int g1 = (ri < 8) ? 2 : 3;                  // tile1: g | o
  const float bias0 = bih[layer * 4096 + g0 * 1024 + jme] + bhh[layer * 4096 + g0 * 1024 + jme];
  const float bias1 = bih[layer * 4096 + g1 * 1024 + jme] + bhh[layer * 4096 + g1 * 1024 + jme];

  float creg[4] = {0.f, 0.f, 0.f, 0.f};

  const unsigned short* lds0 = Wlds + (size_t)lane * 8;
  const unsigned short* lds1 = Wlds + (size_t)64 * 64 * 8 + (size_t)lane * 8;
  const int arow = wid * 16 + ri;
  const bool lo = (ri < 8);

  __syncthreads();                                  // Wlds ready

  if (layer == 0) {
    // ---------------- layer 1: h1(p) = cell(H0(p), h1(p-1)) ----------------
    for (int p = 0; p < Tc; ++p) {
      // free half: A1 = H0(p), K 0..1023 (no dependency; normal cached loads)
      const unsigned short* a1 = H0 + (size_t)p * Bc * Hc + (size_t)arow * Hc + kg * 8;
      f32x4 acc0 = {0,0,0,0}, acc1 = {0,0,0,0};
#pragma unroll
      for (int kk = 0; kk < 32; ++kk) {
        bf16x8 a = *(const bf16x8*)(a1 + kk * 32);
        acc0 = MFMA16(a, *(const bf16x8*)(lds0 + kk * 512), acc0);
        acc1 = MFMA16(a, *(const bf16x8*)(lds1 + kk * 512), acc1);
      }
      // gated half: wait h1(p-1) ready, then L3-coherent loads
      if (tid < 128 && p >= 1) poll_rlx(f1 + tid * 16, p);
      __syncthreads();
      const unsigned short* a2 = h1buf + (size_t)((p - 1) & 3) * Bc * Hc + (size_t)arow * Hc + kg * 8;
#pragma unroll
      for (int kk = 32; kk < 64; ++kk) {
        bf16x8 a = ldg_c(a2 + (kk - 32) * 32);
        acc0 = MFMA16(a, *(const bf16x8*)(lds0 + kk * 512), acc0);
        acc1 = MFMA16(a, *(const bf16x8*)(lds1 + kk * 512), acc1);
      }
      // cell epilogue into registers
      float hn[4];
#pragma unroll
      for (int q = 0; q < 4; ++q) {
        float x0 = acc0[q] + bias0;
        float x1 = acc1[q] + bias1;
        float p0 = __shfl_xor(x0, 8);
        float p1 = __shfl_xor(x1, 8);
        float gi = lo ? x0 : p0;
        float gf = lo ? p0 : x0;
        float gg = lo ? x1 : p1;
        float go = lo ? p1 : x1;
        float cn = sigm(gf) * creg[q] + sigm(gi) * tanhf(gg);
        hn[q] = sigm(go) * tanhf(cn);
        creg[q] = cn;
      }
      // recycle wait: h1buf[p&3] last read by layer-2 step p-4
      if (tid < 128 && p >= 4) poll_rlx(f2 + tid * 16, p - 3);
      __syncthreads();
      unsigned short* hb = h1buf + (size_t)(p & 3) * Bc * Hc;
      if (lo) {
#pragma unroll
        for (int q = 0; q < 4; ++q) {
          const int rr = wid * 16 + kg * 4 + q;
          stg_c(hb + (size_t)rr * Hc + jme, f2bf(hn[q]));
        }
      }
      __syncthreads();                              // pre-barrier vmcnt(0): stores ACKed at L3
      if (tid == 0) sig(f1 + w * 16, p + 1);
    }
  } else {
    // ---------------- layer 2: h2(s) = cell(h1(s), h2(s-1)) ----------------
    for (int s = 0; s < Tc; ++s) {
      // own-chain half first: wait h2(s-1)
      if (tid < 128 && s >= 1) poll_rlx(f2 + tid * 16, s);
      __syncthreads();
      const unsigned short* a2 = h2buf + (size_t)((s - 1) & 3) * Bc * Hc + (size_t)arow * Hc + kg * 8;
      f32x4 acc0 = {0,0,0,0}, acc1 = {0,0,0,0};
#pragma unroll
      for (int kk = 32; kk < 64; ++kk) {
        bf16x8 a = ldg_c(a2 + (kk - 32) * 32);
        acc0 = MFMA16(a, *(const bf16x8*)(lds0 + kk * 512), acc0);
        acc1 = MFMA16(a, *(const bf16x8*)(lds1 + kk * 512), acc1);
      }
      // cross-layer half: wait h1(s)
      if (tid < 128) poll_rlx(f1 + tid * 16, s + 1);
      __syncthreads();
      const unsigned short* a1 = h1buf + (size_t)(s & 3) * Bc * Hc + (size_t)arow * Hc + kg * 8;
#pragma unroll
      for (int kk = 0; kk < 32; ++kk) {
        bf16x8 a = ldg_c(a1 + kk * 32);
        acc0 = MFMA16(a, *(const bf16x8*)(lds0 + kk * 512), acc0);
        acc1 = MFMA16(a, *(const bf16x8*)(lds1 + kk * 512), acc1);
      }
      // cell epilogue + stores
      unsigned short* hb = h2buf + (size_t)(s & 3) * Bc * Hc;
      float* po = out + (size_t)s * Bc * Hc;
#pragma unroll
      for (int q = 0; q < 4; ++q) {
        float x0 = acc0[q] + bias0;
        float x1 = acc1[q] + bias1;
        float p0 = __shfl_xor(x0, 8);
        float p1 = __shfl_xor(x1, 8);
        float gi = lo ? x0 : p0;
        float gf = lo ? p0 : x0;
        float gg = lo ? x1 : p1;
        float go = lo ? p1 : x1;
        float cn = sigm(gf) * creg[q] + sigm(gi) * tanhf(gg);
        float hnv = sigm(go) * tanhf(cn);
        creg[q] = cn;
        const int rr = wid * 16 + kg * 4 + q;
        if (lo) {
          stg_c(hb + (size_t)rr * Hc + jme, f2bf(hnv));
          po[(size_t)rr * Hc + jme] = hnv;          // plain store; never read in-kernel
        }
      }
      __syncthreads();                              // pre-barrier vmcnt(0): stores ACKed at L3
      if (tid == 0) sig(f2 + w * 16, s + 1);
    }
  }
}

// ----------------- launcher -----------------
extern "C" void kernel_launch(void* const* d_in, const int* in_sizes, int n_in,
                              void* d_out, int out_size, void* d_ws, size_t ws_size,
                              hipStream_t stream) {
  const float* x     = (const float*)d_in[0];
  const float* W_ih0 = (const float*)d_in[1];
  // d_in[2] = W_hh0 (unused: layer-0 state is always zero)
  const float* b_ih0 = (const float*)d_in[3];
  const float* b_hh0 = (const float*)d_in[4];
  const float* W_ihr = (const float*)d_in[5];
  const float* W_hhr = (const float*)d_in[6];
  const float* b_ihr = (const float*)d_in[7];
  const float* b_hhr = (const float*)d_in[8];

  char* ws = (char*)d_ws;
  constexpr size_t W0B_OFF = 0;                                  // 4 MB
  constexpr size_t XB_OFF  = W0B_OFF + (size_t)4096 * 512 * 2;   // 32 MB
  constexpr size_t B0S_OFF = XB_OFF + (size_t)Bc * Tc * Ec * 2;  // 16 KB
  constexpr size_t H1B_OFF = B0S_OFF + 4096 * 4;                 // 1 MB
  constexpr size_t H2B_OFF = H1B_OFF + (size_t)4 * Bc * Hc * 2;  // 1 MB
  constexpr size_t F1_OFF  = H2B_OFF + (size_t)4 * Bc * Hc * 2;  // 8 KB
  constexpr size_t F2_OFF  = F1_OFF + 128 * 16 * 4;              // 8 KB

  unsigned short* W0b = (unsigned short*)(ws + W0B_OFF);
  unsigned short* xb  = (unsigned short*)(ws + XB_OFF);
  float* b0s = (float*)(ws + B0S_OFF);
  unsigned short* h1buf = (unsigned short*)(ws + H1B_OFF);
  unsigned short* h2buf = (unsigned short*)(ws + H2B_OFF);
  int* f1 = (int*)(ws + F1_OFF);
  int* f2 = (int*)(ws + F2_OFF);

  // H0 (bf16 [T][B][H], 64 MB) lives in the upper half of d_out. out[s] (written at
  // layer-2 step s, after f1 >= s+1) only overlaps H0[q] for q = 2(s-128)+{0,1} <= s,
  // i.e. strictly after layer 1 finished reading H0[q]. Verified byte-exact.
  unsigned short* H0 = (unsigned short*)d_out + (size_t)Tc * Bc * Hc;
  float* out = (float*)d_out;

  int n0 = 4096 * 512;
  k_cvt_bf16<<<n0 / 1024, 256, 0, stream>>>(W_ih0, W0b, n0);
  int nx = Bc * Tc * Ec;
  k_cvt_bf16<<<nx / 1024, 256, 0, stream>>>(x, xb, nx);
  k_prep_small<<<2048, 256, 0, stream>>>(b_ih0, b_hh0, b0s, h1buf, h2buf, f1, f2);
  k_l0<<<dim3(1024, 16), 512, 0, stream>>>(xb, W0b, b0s, H0);

  const float* Wih = W_ihr; const float* Whh = W_hhr;
  const float* bih = b_ihr; const float* bhh = b_hhr;
  void* kargs[] = { &H0, &Wih, &Whh, &bih, &bhh, &h1buf, &h2buf, &f1, &f2, &out };
  hipLaunchCooperativeKernel((void*)k_rec, dim3(256), dim3(512), kargs, 0, stream);
}